// Round 15
// baseline (849.560 us; speedup 1.0000x reference)
//
#include <hip/hip_runtime.h>

// Problem constants (fixed by the reference)
#define C_ROW 128            // lv rows: wids values lie in [0,128)
#define C_TOT 160            // combined rows feeding the scatter
#define R_    64
#define D_    4096
#define B_TOK 256
#define NENT  (C_TOT * R_)   // 10240 scatter entries
#define KS    64             // k-split for stage 1
#define KSPAN (D_ / KS)      // 64 floats per slice
#define LVN   (C_ROW * R_)   // 8192 lv entries
#define ECAP  128            // ELL capacity per token (mean 40, max ~75)
#define CH    8              // D-chunks per token in stage 2
#define NFILT 256            // filter blocks merged into the S1 launch

typedef float float4v __attribute__((ext_vector_type(4)));
typedef float float2v __attribute__((ext_vector_type(2)));

// Device-global scratch (capture-safe; fully rewritten every call).
// g_done starts zeroed (static init) and is reset to 0 in-call by the
// winning block, so graph replays see a clean state.
__device__ float g_lvp[KS][LVN];      // stage-1 partials, 2 MB
__device__ float g_lv[LVN];           // reduced lv table, 32 KB
__device__ int   g_done[C_ROW];       // per-row completion counters
__device__ int   g_ent[B_TOK][ECAP];  // ELL entry lists (lv/B row index)
__device__ int   g_cnt[B_TOK];        // entries per token

// ---------------------------------------------------------------------------
// S1 launch: blocks 0..255 = per-token ELL filter (overlapped with S1);
// blocks 256..8447 = lv partials (R12 verified body). The LAST finishing
// block of each lv row folds that row's 64 partials -> g_lv in-kernel
// (canonical threadfence + done-counter pattern; no spin, losers exit).
// ---------------------------------------------------------------------------
__global__ __launch_bounds__(256) void s1(const float* __restrict__ A,
                                          const float* __restrict__ x,
                                          const int* __restrict__ xids,
                                          const int* __restrict__ wids) {
  const int blk = blockIdx.x;
  const int tid = threadIdx.x;

  if (blk < NFILT) {                   // ---- ELL filter block (R10 verified)
    const int t = blk;
    __shared__ int s_n;
    if (tid == 0) s_n = 0;
    __syncthreads();
    for (int i = tid; i < NENT; i += 256) {
      if (xids[i] == t) {
        const int p = atomicAdd(&s_n, 1);
        if (p < ECAP) g_ent[t][p] = wids[i >> 6] * R_ + (i & 63);
      }
    }
    __syncthreads();
    if (tid == 0) g_cnt[t] = (s_n < ECAP) ? s_n : ECAP;
    return;
  }

  // ---- S1 block (R12 verified body)
  const int b  = blk - NFILT;
  const int c  = b >> 6;             // lv row, c < 128
  const int ks = b & (KS - 1);       // k-slice
  const int r  = tid & 63;
  const int wv = tid >> 6;

  __shared__ int     s_tok[64];
  __shared__ float4v xs[64][KSPAN / 4];   // [row][swizzled float4 col] 16 KB
  __shared__ float   part[4][64];

  if (tid < 64) s_tok[tid] = xids[c * R_ + tid];
  __syncthreads();

  const int k0 = ks * KSPAN;                // float offset within a row
  #pragma unroll
  for (int i = 0; i < 4; ++i) {
    const int flat = i * 256 + tid;
    const int row  = flat >> 4;             // 0..63
    const int c4   = flat & 15;             // float4 col 0..15
    xs[row][c4 ^ (row & 7)] = *reinterpret_cast<const float4v*>(
        x + (size_t)s_tok[row] * D_ + k0 + c4 * 4);
  }
  __syncthreads();

  const int a = wids[c];
  const float* __restrict__ acol =
      A + (size_t)a * (D_ * R_) + (size_t)k0 * R_ + r;

  float acc = 0.f;
  #pragma unroll
  for (int j4 = 0; j4 < 4; ++j4) {
    const int j = wv * 4 + j4;              // logical float4 col 0..15
    const float4v xv = xs[r][j ^ (r & 7)];
    const int kk = j * 4;
    acc = fmaf(xv[0], acol[(size_t)(kk + 0) * R_], acc);
    acc = fmaf(xv[1], acol[(size_t)(kk + 1) * R_], acc);
    acc = fmaf(xv[2], acol[(size_t)(kk + 2) * R_], acc);
    acc = fmaf(xv[3], acol[(size_t)(kk + 3) * R_], acc);
  }

  part[wv][r] = acc;
  __syncthreads();
  if (tid < 64)
    g_lvp[ks][c * R_ + tid] =
        part[0][tid] + part[1][tid] + part[2][tid] + part[3][tid];

  // ---- last-block-done fold for this lv row
  __syncthreads();
  __threadfence();                     // make this block's slice device-visible
  __shared__ int s_last;
  if (tid == 0) {
    const int d = __hip_atomic_fetch_add(&g_done[c], 1, __ATOMIC_ACQ_REL,
                                         __HIP_MEMORY_SCOPE_AGENT);
    s_last = (d == KS - 1);
    if (s_last) g_done[c] = 0;         // reset for the next graph replay
  }
  __syncthreads();
  if (!s_last) return;

  // fold row c: 64 entries x 64 partial tables (coalesced, 4-wave parallel)
  const int pg = tid >> 6;             // 0..3: partial-table group
  const int e  = tid & 63;             // lv entry within row
  float s = 0.f;
  #pragma unroll
  for (int p = 0; p < 16; ++p) s += g_lvp[pg * 16 + p][c * R_ + e];
  part[pg][e] = s;
  __syncthreads();
  if (tid < 64)
    g_lv[c * R_ + tid] =
        part[0][tid] + part[1][tid] + part[2][tid] + part[3][tid];
}

// ---------------------------------------------------------------------------
// S2: per-token gather. grid = B_TOK*CH = 2048 blocks, 256 threads
// -> full 32 waves/CU. Each block: one token, 512 floats (float2/thread).
// (R12 verified body, unchanged.)
// ---------------------------------------------------------------------------
__global__ __launch_bounds__(256) void s2(const float* __restrict__ Bm,
                                          float* __restrict__ out) {
  const int t   = blockIdx.x >> 3;
  const int ch  = blockIdx.x & (CH - 1);
  const int tid = threadIdx.x;
  const int d0  = ch * (D_ / CH) + tid * 2;

  const int n = g_cnt[t];

  __shared__ int   s_idx[ECAP];
  __shared__ float s_cf[ECAP];
  if (tid < n) {
    const int idx = g_ent[t][tid];
    s_idx[tid] = idx;
    s_cf[tid]  = g_lv[idx];
  }
  __syncthreads();

  float a0 = 0.f, a1 = 0.f;
  #pragma unroll 4
  for (int j = 0; j < n; ++j) {
    const int   idx = s_idx[j];
    const float cf  = s_cf[j];
    const float2v bv =
        *reinterpret_cast<const float2v*>(Bm + (size_t)idx * D_ + d0);
    a0 = fmaf(cf, bv[0], a0);
    a1 = fmaf(cf, bv[1], a1);
  }

  float2v o;
  o[0] = 2.0f * a0;
  o[1] = 2.0f * a1;
  *reinterpret_cast<float2v*>(out + (size_t)t * D_ + d0) = o;
}

// ---------------------------------------------------------------------------
extern "C" void kernel_launch(void* const* d_in, const int* in_sizes, int n_in,
                              void* d_out, int out_size, void* d_ws, size_t ws_size,
                              hipStream_t stream) {
  const float* lora_A = (const float*)d_in[0];
  const float* lora_B = (const float*)d_in[1];
  const float* x      = (const float*)d_in[2];
  const int* xids = (const int*)d_in[3];
  const int* wids = (const int*)d_in[4];
  float* out = (float*)d_out;

  hipLaunchKernelGGL(s1, dim3(C_ROW * KS + NFILT), dim3(256), 0, stream,
                     lora_A, x, xids, wids);
  hipLaunchKernelGGL(s2, dim3(B_TOK * CH), dim3(256), 0, stream,
                     lora_B, out);
}

// Round 16
// 56.401 us; speedup vs baseline: 15.0628x; 15.0628x over previous
//
#include <hip/hip_runtime.h>

// Problem constants (fixed by the reference)
#define C_ROW 128            // lv rows: wids values lie in [0,128)
#define C_TOT 160            // combined rows feeding the scatter
#define R_    64
#define D_    4096
#define B_TOK 256
#define NENT  (C_TOT * R_)   // 10240 scatter entries
#define KS    64             // k-split for stage 1
#define KSPAN (D_ / KS)      // 64 floats per slice
#define LVN   (C_ROW * R_)   // 8192 lv entries
#define ECAP  128            // ELL capacity per token (mean 40, max ~75)
#define CH    8              // D-chunks per token in stage 2
#define NFILT 256            // filter blocks merged into the S1 launch

typedef float float4v __attribute__((ext_vector_type(4)));
typedef float float2v __attribute__((ext_vector_type(2)));

// Device-global scratch (capture-safe; fully rewritten every call).
__device__ float g_lvp[KS][LVN];      // stage-1 partials, 2 MB
__device__ float g_lv[LVN];           // reduced lv table, 32 KB
__device__ int   g_ent[B_TOK][ECAP];  // ELL entry lists (lv/B row index)
__device__ int   g_cnt[B_TOK];        // entries per token

// ---------------------------------------------------------------------------
// S1 launch: blocks 0..255 = per-token ELL filter (overlapped with S1);
// blocks 256..8447 = lv partials, KS=64 -> 16 KB x-tile -> 32 waves/CU.
// Plain partial-store epilogue; ordering via the kernel boundary (cheapest
// sync on this chip -- device fences/atomics measured 15x-50x worse).
// ---------------------------------------------------------------------------
__global__ __launch_bounds__(256) void s1(const float* __restrict__ A,
                                          const float* __restrict__ x,
                                          const int* __restrict__ xids,
                                          const int* __restrict__ wids) {
  const int blk = blockIdx.x;
  const int tid = threadIdx.x;

  if (blk < NFILT) {                   // ---- ELL filter block
    const int t = blk;
    __shared__ int s_n;
    if (tid == 0) s_n = 0;
    __syncthreads();
    for (int i = tid; i < NENT; i += 256) {
      if (xids[i] == t) {
        const int p = atomicAdd(&s_n, 1);
        if (p < ECAP) g_ent[t][p] = wids[i >> 6] * R_ + (i & 63);
      }
    }
    __syncthreads();
    if (tid == 0) g_cnt[t] = (s_n < ECAP) ? s_n : ECAP;
    return;
  }

  // ---- S1 block
  const int b  = blk - NFILT;
  const int c  = b >> 6;             // lv row, c < 128
  const int ks = b & (KS - 1);       // k-slice
  const int r  = tid & 63;
  const int wv = tid >> 6;

  __shared__ int     s_tok[64];
  __shared__ float4v xs[64][KSPAN / 4];   // [row][swizzled float4 col] 16 KB
  __shared__ float   part[4][64];

  if (tid < 64) s_tok[tid] = xids[c * R_ + tid];
  __syncthreads();

  const int k0 = ks * KSPAN;                // float offset within a row
  #pragma unroll
  for (int i = 0; i < 4; ++i) {
    const int flat = i * 256 + tid;
    const int row  = flat >> 4;             // 0..63
    const int c4   = flat & 15;             // float4 col 0..15
    xs[row][c4 ^ (row & 7)] = *reinterpret_cast<const float4v*>(
        x + (size_t)s_tok[row] * D_ + k0 + c4 * 4);
  }
  __syncthreads();

  const int a = wids[c];
  const float* __restrict__ acol =
      A + (size_t)a * (D_ * R_) + (size_t)k0 * R_ + r;

  float acc = 0.f;
  #pragma unroll
  for (int j4 = 0; j4 < 4; ++j4) {
    const int j = wv * 4 + j4;              // logical float4 col 0..15
    const float4v xv = xs[r][j ^ (r & 7)];
    const int kk = j * 4;
    acc = fmaf(xv[0], acol[(size_t)(kk + 0) * R_], acc);
    acc = fmaf(xv[1], acol[(size_t)(kk + 1) * R_], acc);
    acc = fmaf(xv[2], acol[(size_t)(kk + 2) * R_], acc);
    acc = fmaf(xv[3], acol[(size_t)(kk + 3) * R_], acc);
  }

  part[wv][r] = acc;
  __syncthreads();
  if (tid < 64)
    g_lvp[ks][c * R_ + tid] =
        part[0][tid] + part[1][tid] + part[2][tid] + part[3][tid];
}

// ---------------------------------------------------------------------------
// FOLD: collapse the KS partials -> g_lv. grid = 32 blocks, coalesced.
// ---------------------------------------------------------------------------
__global__ __launch_bounds__(256) void fold() {
  const int i = blockIdx.x * 256 + threadIdx.x;
  float s = 0.f;
  #pragma unroll 8
  for (int p = 0; p < KS; ++p) s += g_lvp[p][i];
  g_lv[i] = s;
}

// ---------------------------------------------------------------------------
// S2: per-token gather. grid = B_TOK*CH = 2048 blocks, 256 threads
// -> full 32 waves/CU. Each block: one token, 512 floats (float2/thread).
// ---------------------------------------------------------------------------
__global__ __launch_bounds__(256) void s2(const float* __restrict__ Bm,
                                          float* __restrict__ out) {
  const int t   = blockIdx.x >> 3;
  const int ch  = blockIdx.x & (CH - 1);
  const int tid = threadIdx.x;
  const int d0  = ch * (D_ / CH) + tid * 2;

  const int n = g_cnt[t];

  __shared__ int   s_idx[ECAP];
  __shared__ float s_cf[ECAP];
  if (tid < n) {
    const int idx = g_ent[t][tid];
    s_idx[tid] = idx;
    s_cf[tid]  = g_lv[idx];
  }
  __syncthreads();

  float a0 = 0.f, a1 = 0.f;
  #pragma unroll 4
  for (int j = 0; j < n; ++j) {
    const int   idx = s_idx[j];
    const float cf  = s_cf[j];
    const float2v bv =
        *reinterpret_cast<const float2v*>(Bm + (size_t)idx * D_ + d0);
    a0 = fmaf(cf, bv[0], a0);
    a1 = fmaf(cf, bv[1], a1);
  }

  float2v o;
  o[0] = 2.0f * a0;
  o[1] = 2.0f * a1;
  *reinterpret_cast<float2v*>(out + (size_t)t * D_ + d0) = o;
}

// ---------------------------------------------------------------------------
extern "C" void kernel_launch(void* const* d_in, const int* in_sizes, int n_in,
                              void* d_out, int out_size, void* d_ws, size_t ws_size,
                              hipStream_t stream) {
  const float* lora_A = (const float*)d_in[0];
  const float* lora_B = (const float*)d_in[1];
  const float* x      = (const float*)d_in[2];
  const int* xids = (const int*)d_in[3];
  const int* wids = (const int*)d_in[4];
  float* out = (float*)d_out;

  hipLaunchKernelGGL(s1, dim3(C_ROW * KS + NFILT), dim3(256), 0, stream,
                     lora_A, x, xids, wids);
  hipLaunchKernelGGL(fold, dim3(LVN / 256), dim3(256), 0, stream);
  hipLaunchKernelGGL(s2, dim3(B_TOK * CH), dim3(256), 0, stream,
                     lora_B, out);
}

// Round 17
// 46.622 us; speedup vs baseline: 18.2222x; 1.2097x over previous
//
#include <hip/hip_runtime.h>

// Problem constants (fixed by the reference)
#define C_ROW 128            // lv rows: wids values lie in [0,128)
#define C_TOT 160            // combined rows feeding the scatter
#define R_    64
#define D_    4096
#define B_TOK 256
#define NENT  (C_TOT * R_)   // 10240 scatter entries
#define KS    32             // k-split for stage 1
#define KSPAN (D_ / KS)      // 128 floats per slice
#define LVN   (C_ROW * R_)   // 8192 lv entries
#define ECAP  128            // ELL capacity per token (mean 40, max ~75)
#define CH    8              // D-chunks per token in stage 2
#define NFILT 256            // filter blocks merged into the S1 launch

typedef float float4v __attribute__((ext_vector_type(4)));
typedef float float2v __attribute__((ext_vector_type(2)));

// Device-global scratch (capture-safe; fully rewritten every call).
__device__ float g_lvp[KS][LVN];      // stage-1 partials, 1 MB
__device__ float g_lv[LVN];           // reduced lv table, 32 KB
__device__ int   g_ent[B_TOK][ECAP];  // ELL entry lists (lv/B row index)
__device__ int   g_cnt[B_TOK];        // entries per token

// ---------------------------------------------------------------------------
// S1 launch (512-thread blocks): blocks 0..255 = per-token ELL filter;
// blocks 256..4351 = lv partials, KS=32 -> 32 KB x-tile, 8 waves/block,
// 4 blocks/CU = full 32 waves/CU (tests R8's tile-size at iso-occupancy).
// ---------------------------------------------------------------------------
__global__ __launch_bounds__(512) void s1(const float* __restrict__ A,
                                          const float* __restrict__ x,
                                          const int* __restrict__ xids,
                                          const int* __restrict__ wids) {
  const int blk = blockIdx.x;
  const int tid = threadIdx.x;

  if (blk < NFILT) {                   // ---- ELL filter block
    const int t = blk;
    __shared__ int s_n;
    if (tid == 0) s_n = 0;
    __syncthreads();
    for (int i = tid; i < NENT; i += 512) {
      if (xids[i] == t) {
        const int p = atomicAdd(&s_n, 1);
        if (p < ECAP) g_ent[t][p] = wids[i >> 6] * R_ + (i & 63);
      }
    }
    __syncthreads();
    if (tid == 0) g_cnt[t] = (s_n < ECAP) ? s_n : ECAP;
    return;
  }

  // ---- S1 block
  const int b  = blk - NFILT;
  const int c  = b >> 5;             // lv row, c < 128
  const int ks = b & (KS - 1);       // k-slice
  const int r  = tid & 63;
  const int wv = tid >> 6;           // wave 0..7

  __shared__ int     s_tok[64];
  __shared__ float4v xs[64][KSPAN / 4];   // [row][swizzled float4 col] 32 KB
  __shared__ float   part[8][64];

  if (tid < 64) s_tok[tid] = xids[c * R_ + tid];
  __syncthreads();

  const int k0 = ks * KSPAN;                // float offset within a row
  // Stage: 2048 float4s, 4 iters x 512 thr; 32 lanes sweep one row's 512 B.
  #pragma unroll
  for (int i = 0; i < 4; ++i) {
    const int flat = i * 512 + tid;
    const int row  = flat >> 5;             // 0..63
    const int c4   = flat & 31;             // float4 col 0..31
    xs[row][c4 ^ (row & 7)] = *reinterpret_cast<const float4v*>(
        x + (size_t)s_tok[row] * D_ + k0 + c4 * 4);
  }
  __syncthreads();

  const int a = wids[c];
  const float* __restrict__ acol =
      A + (size_t)a * (D_ * R_) + (size_t)k0 * R_ + r;

  // Wave wv covers float4 cols wv*4 .. wv*4+3 (16 k's, 16 A-loads, 16 FMAs).
  float acc = 0.f;
  #pragma unroll
  for (int j4 = 0; j4 < 4; ++j4) {
    const int j = wv * 4 + j4;              // logical float4 col 0..31
    const float4v xv = xs[r][j ^ (r & 7)];
    const int kk = j * 4;
    acc = fmaf(xv[0], acol[(size_t)(kk + 0) * R_], acc);
    acc = fmaf(xv[1], acol[(size_t)(kk + 1) * R_], acc);
    acc = fmaf(xv[2], acol[(size_t)(kk + 2) * R_], acc);
    acc = fmaf(xv[3], acol[(size_t)(kk + 3) * R_], acc);
  }

  part[wv][r] = acc;
  __syncthreads();
  if (tid < 64) {
    float s = 0.f;
    #pragma unroll
    for (int p = 0; p < 8; ++p) s += part[p][tid];
    g_lvp[ks][c * R_ + tid] = s;
  }
}

// ---------------------------------------------------------------------------
// FOLD: collapse the KS partials -> g_lv. grid = 32 blocks, coalesced.
// ---------------------------------------------------------------------------
__global__ __launch_bounds__(256) void fold() {
  const int i = blockIdx.x * 256 + threadIdx.x;
  float s = 0.f;
  #pragma unroll 8
  for (int p = 0; p < KS; ++p) s += g_lvp[p][i];
  g_lv[i] = s;
}

// ---------------------------------------------------------------------------
// S2: per-token gather. grid = B_TOK*CH = 2048 blocks, 256 threads
// -> full 32 waves/CU. Each block: one token, 512 floats (float2/thread).
// (R12 verified body, unchanged.)
// ---------------------------------------------------------------------------
__global__ __launch_bounds__(256) void s2(const float* __restrict__ Bm,
                                          float* __restrict__ out) {
  const int t   = blockIdx.x >> 3;
  const int ch  = blockIdx.x & (CH - 1);
  const int tid = threadIdx.x;
  const int d0  = ch * (D_ / CH) + tid * 2;

  const int n = g_cnt[t];

  __shared__ int   s_idx[ECAP];
  __shared__ float s_cf[ECAP];
  if (tid < n) {
    const int idx = g_ent[t][tid];
    s_idx[tid] = idx;
    s_cf[tid]  = g_lv[idx];
  }
  __syncthreads();

  float a0 = 0.f, a1 = 0.f;
  #pragma unroll 4
  for (int j = 0; j < n; ++j) {
    const int   idx = s_idx[j];
    const float cf  = s_cf[j];
    const float2v bv =
        *reinterpret_cast<const float2v*>(Bm + (size_t)idx * D_ + d0);
    a0 = fmaf(cf, bv[0], a0);
    a1 = fmaf(cf, bv[1], a1);
  }

  float2v o;
  o[0] = 2.0f * a0;
  o[1] = 2.0f * a1;
  *reinterpret_cast<float2v*>(out + (size_t)t * D_ + d0) = o;
}

// ---------------------------------------------------------------------------
extern "C" void kernel_launch(void* const* d_in, const int* in_sizes, int n_in,
                              void* d_out, int out_size, void* d_ws, size_t ws_size,
                              hipStream_t stream) {
  const float* lora_A = (const float*)d_in[0];
  const float* lora_B = (const float*)d_in[1];
  const float* x      = (const float*)d_in[2];
  const int* xids = (const int*)d_in[3];
  const int* wids = (const int*)d_in[4];
  float* out = (float*)d_out;

  hipLaunchKernelGGL(s1, dim3(C_ROW * KS + NFILT), dim3(512), 0, stream,
                     lora_A, x, xids, wids);
  hipLaunchKernelGGL(fold, dim3(LVN / 256), dim3(256), 0, stream);
  hipLaunchKernelGGL(s2, dim3(B_TOK * CH), dim3(256), 0, stream,
                     lora_B, out);
}